// Round 2
// baseline (605.138 us; speedup 1.0000x reference)
//
#include <hip/hip_runtime.h>
#include <stdint.h>

// AM-softmax loss, fused on MI355X (gfx950) — round 2.
//
// Structure change vs round 1: grid = (782 C-tiles, 2 row-halves). Each block
// stages one 128-class B tile (fp32 W -> bf16, inline, coalesced) into LDS
// ONCE, then loops over 8 row-blocks of A (A frags straight from L2-resident
// xnb). 16x more MFMA work per staged byte; prep_w kernel deleted.
// Row-sums of exp(S*wf) go directly to global atomicAdd (no LDS rowsum, no
// in-loop barriers — exactly one __syncthreads per block).
// 16-lane reduction now uses full-rate VALU DPP (row_ror:8/4 + quad_perm)
// instead of ds_swizzle shuffles (moves work off the LDS pipe).

constexpr int N  = 2048;
constexpr int D  = 192;
constexpr int C  = 100000;
constexpr int KP = 200;               // padded K stride (bf16): 400 B rows
constexpr int CT = (C + 127) / 128;   // 782 column tiles
constexpr int RB = 8;                 // row-blocks per block (grid.y = 2)

#define S_SCALE 30.0f
#define MARGIN  0.2f

using short8 = __attribute__((ext_vector_type(8))) short;   // 8 bf16 (4 VGPRs)
using f32x4  = __attribute__((ext_vector_type(4))) float;   // MFMA C/D

__device__ inline unsigned short f2bf(float f) {  // fp32 -> bf16 RNE
  unsigned int u = __float_as_uint(f);
  u += 0x7fffu + ((u >> 16) & 1u);
  return (unsigned short)(u >> 16);
}

// Sum across each 16-lane DPP row; result valid in all 16 lanes.
__device__ inline float row_sum16(float v) {
  int x;
  x = __float_as_int(v);
  v += __int_as_float(__builtin_amdgcn_update_dpp(0, x, 0x128, 0xF, 0xF, true)); // row_ror:8
  x = __float_as_int(v);
  v += __int_as_float(__builtin_amdgcn_update_dpp(0, x, 0x124, 0xF, 0xF, true)); // row_ror:4
  x = __float_as_int(v);
  v += __int_as_float(__builtin_amdgcn_update_dpp(0, x, 0x04E, 0xF, 0xF, true)); // quad_perm xor2
  x = __float_as_int(v);
  v += __int_as_float(__builtin_amdgcn_update_dpp(0, x, 0x0B1, 0xF, 0xF, true)); // quad_perm xor1
  return v;
}

// ---------------- prep: normalize x rows, convert to padded bf16 ----------
__global__ __launch_bounds__(256) void prep_x(const float* __restrict__ x,
                                              unsigned short* __restrict__ xnb) {
  const int row  = blockIdx.x * 4 + (threadIdx.x >> 6);
  const int lane = threadIdx.x & 63;
  const float* xr = x + (size_t)row * D;
  float v0 = xr[lane], v1 = xr[lane + 64], v2 = xr[lane + 128];
  float ss = v0 * v0 + v1 * v1 + v2 * v2;
#pragma unroll
  for (int off = 32; off > 0; off >>= 1) ss += __shfl_xor(ss, off, 64);
  const float inv = rsqrtf(ss);
  unsigned short* o = xnb + (size_t)row * KP;
  o[lane]       = f2bf(v0 * inv);
  o[lane + 64]  = f2bf(v1 * inv);
  o[lane + 128] = f2bf(v2 * inv);
  if (lane < KP - D) o[D + lane] = 0;
}

// ---------------- main fused GEMM + exp-rowsum ----------------------------
// grid = (CT, 2); block = 256 (4 waves, 2x2 quadrants of 64x64).
__global__ __launch_bounds__(256, 3) void gemm_lse(
    const unsigned short* __restrict__ xnb,  // [N][KP] bf16
    const float* __restrict__ Wf,            // [C][D] fp32
    float* __restrict__ sumexp) {            // [N] fp32, pre-zeroed
  __shared__ alignas(16) unsigned short Bs[128 * KP];  // 51.2 KB

  const int tid    = threadIdx.x;
  const int colblk = blockIdx.x;
  const int ybase  = blockIdx.y;             // 0 or 1 (row half)

  // ---- stage B tile once: fp32 W -> bf16 LDS, fully coalesced loads ----
  {
    const int cbase = colblk * 128;
#pragma unroll
    for (int i = 0; i < 24; ++i) {           // 6144 float4 = 128 rows x 48
      const int g   = tid + i * 256;
      const int row = g / 48;
      const int k4  = (g - row * 48) * 4;    // float offset within row
      const int rg  = cbase + row;
      float4 f = (rg < C) ? ((const float4*)(Wf + (size_t)rg * D))[k4 >> 2]
                          : make_float4(0.f, 0.f, 0.f, 0.f);
      ushort4 h;
      h.x = f2bf(f.x); h.y = f2bf(f.y); h.z = f2bf(f.z); h.w = f2bf(f.w);
      *(ushort4*)(&Bs[row * KP + k4]) = h;
    }
    // zero the K padding region [192,200)
    const int pr = tid >> 1, ph = (tid & 1) * 4;
    *(ushort4*)(&Bs[pr * KP + D + ph]) = make_ushort4(0, 0, 0, 0);
  }
  __syncthreads();  // the ONLY barrier in this kernel

  const int lane = tid & 63;
  const int wave = tid >> 6;
  const int m    = lane & 15;   // A row / B col within 16-tile
  const int quad = lane >> 4;   // k base = quad*8; C/D row base = quad*4
  const int wr   = wave >> 1;   // row half (64) of the 128x128 tile
  const int wc   = wave & 1;    // col half (64)

  const unsigned short* bbase = &Bs[(wc * 64 + m) * KP + quad * 8];
  const int colbase = colblk * 128 + wc * 64 + m;
  const f32x4 zero4 = {0.0f, 0.0f, 0.0f, 0.0f};

  for (int rb = 0; rb < RB; ++rb) {
    const int rowg = ybase * 1024 + rb * 128 + wr * 64;     // this wave's rows
    const unsigned short* abase = xnb + (size_t)(rowg + m) * KP + quad * 8;

    f32x4 acc[4][4];
#pragma unroll
    for (int a = 0; a < 4; ++a)
#pragma unroll
      for (int b = 0; b < 4; ++b) acc[a][b] = zero4;

#pragma unroll
    for (int ks = 0; ks < 6; ++ks) {  // K = 6 * 32
      short8 af[4], bf[4];
#pragma unroll
      for (int t = 0; t < 4; ++t)
        af[t] = *(const short8*)(abase + t * 16 * KP + ks * 32);
#pragma unroll
      for (int t = 0; t < 4; ++t)
        bf[t] = *(const short8*)(bbase + t * 16 * KP + ks * 32);
#pragma unroll
      for (int tr = 0; tr < 4; ++tr)
#pragma unroll
        for (int tc = 0; tc < 4; ++tc)
          acc[tr][tc] = __builtin_amdgcn_mfma_f32_16x16x32_bf16(
              af[tr], bf[tc], acc[tr][tc], 0, 0, 0);
    }

    // Epilogue: exp(S*wf), mask phantom cols, DPP 16-lane reduce, one
    // global atomicAdd per row (from the m==0 lane of each quad).
#pragma unroll
    for (int tr = 0; tr < 4; ++tr) {
      float r0 = 0.f, r1 = 0.f, r2 = 0.f, r3 = 0.f;
#pragma unroll
      for (int tc = 0; tc < 4; ++tc) {
        if (colbase + tc * 16 < C) {
          r0 += __expf(S_SCALE * acc[tr][tc][0]);
          r1 += __expf(S_SCALE * acc[tr][tc][1]);
          r2 += __expf(S_SCALE * acc[tr][tc][2]);
          r3 += __expf(S_SCALE * acc[tr][tc][3]);
        }
      }
      r0 = row_sum16(r0);
      r1 = row_sum16(r1);
      r2 = row_sum16(r2);
      r3 = row_sum16(r3);
      if (m == 0) {
        const int rg = rowg + tr * 16 + quad * 4;
        atomicAdd(&sumexp[rg + 0], r0);
        atomicAdd(&sumexp[rg + 1], r1);
        atomicAdd(&sumexp[rg + 2], r2);
        atomicAdd(&sumexp[rg + 3], r3);
      }
    }
  }
}

// ---------------- per-row finalize ---------------------------------------
__global__ __launch_bounds__(256) void finalize_rows(
    const float* __restrict__ x, const float* __restrict__ W,
    const int* __restrict__ label, const float* __restrict__ sumexp,
    float* __restrict__ Lrow) {
  const int row  = blockIdx.x * 4 + (threadIdx.x >> 6);
  const int lane = threadIdx.x & 63;
  const float* xr = x + (size_t)row * D;
  float v0 = xr[lane], v1 = xr[lane + 64], v2 = xr[lane + 128];
  float ss = v0 * v0 + v1 * v1 + v2 * v2;
  const int lab = label[row];
  const float* wr = W + (size_t)lab * D;
  float d = v0 * wr[lane] + v1 * wr[lane + 64] + v2 * wr[lane + 128];
#pragma unroll
  for (int off = 32; off > 0; off >>= 1) {
    ss += __shfl_xor(ss, off, 64);
    d  += __shfl_xor(d,  off, 64);
  }
  if (lane == 0) {
    const float tgt   = d * rsqrtf(ss);
    const float numer = S_SCALE * (tgt - MARGIN);
    // swap label column: remove its plain-logit exp, add margin-adjusted exp
    const float se = sumexp[row] - __expf(S_SCALE * tgt) + __expf(numer);
    Lrow[row] = numer - logf(se);
  }
}

__global__ __launch_bounds__(256) void reduce_loss(const float* __restrict__ Lrow,
                                                   float* __restrict__ out) {
  const int tid = threadIdx.x;
  float s = 0.0f;
  for (int i = tid; i < N; i += 256) s += Lrow[i];
#pragma unroll
  for (int off = 32; off > 0; off >>= 1) s += __shfl_xor(s, off, 64);
  __shared__ float part[4];
  if ((tid & 63) == 0) part[tid >> 6] = s;
  __syncthreads();
  if (tid == 0) out[0] = -(part[0] + part[1] + part[2] + part[3]) / (float)N;
}

// ---------------- host ----------------------------------------------------
extern "C" void kernel_launch(void* const* d_in, const int* in_sizes, int n_in,
                              void* d_out, int out_size, void* d_ws, size_t ws_size,
                              hipStream_t stream) {
  const float* x     = (const float*)d_in[0];
  const float* W     = (const float*)d_in[1];
  const int*   label = (const int*)d_in[2];
  float*       out   = (float*)d_out;

  char* ws = (char*)d_ws;
  size_t off = 0;
  unsigned short* xnb = (unsigned short*)(ws + off); off += (size_t)N * KP * 2;
  float* sumexp = (float*)(ws + off); off += (size_t)N * 4;
  float* Lrow   = (float*)(ws + off);

  hipMemsetAsync(sumexp, 0, N * sizeof(float), stream);
  prep_x<<<N / 4, 256, 0, stream>>>(x, xnb);

  dim3 grid(CT, 2);
  gemm_lse<<<grid, 256, 0, stream>>>(xnb, W, sumexp);

  finalize_rows<<<N / 4, 256, 0, stream>>>(x, W, label, sumexp, Lrow);
  reduce_loss<<<1, 256, 0, stream>>>(Lrow, out);
}

// Round 3
// 365.802 us; speedup vs baseline: 1.6543x; 1.6543x over previous
//
#include <hip/hip_runtime.h>
#include <stdint.h>

// AM-softmax loss, fused on MI355X (gfx950) — round 3.
//
// vs round 2: global atomicAdd accumulation (3.2M device-scope RMWs onto 2048
// words -> cross-XCD line ping-pong, 109 MB HBM writes, MfmaUtil 5%) replaced
// by contention-free partial stores: partial[row][2*colblk + wc] written
// exactly once, reduced by a tiny follow-up kernel. Grid rebalanced to
// (782, 4) / RB=4 for ~12 blocks/CU of parallelism. B staged once per block
// straight from fp32 W (inline bf16 convert, coalesced); one barrier/block.

constexpr int N  = 2048;
constexpr int D  = 192;
constexpr int C  = 100000;
constexpr int KP = 200;               // padded K stride (bf16)
constexpr int CT = (C + 127) / 128;   // 782 column tiles
constexpr int RB = 4;                 // row-blocks per block (grid.y = 4)
constexpr int PC  = 2 * CT;           // 1564 partial slots per row
constexpr int PCP = 1568;             // padded (x4B = 6272B row stride)

#define S_SCALE 30.0f
#define MARGIN  0.2f

using short8 = __attribute__((ext_vector_type(8))) short;   // 8 bf16 (4 VGPRs)
using f32x4  = __attribute__((ext_vector_type(4))) float;   // MFMA C/D

__device__ inline unsigned short f2bf(float f) {  // fp32 -> bf16 RNE
  unsigned int u = __float_as_uint(f);
  u += 0x7fffu + ((u >> 16) & 1u);
  return (unsigned short)(u >> 16);
}

// Sum across each 16-lane DPP row; result valid in all 16 lanes.
__device__ inline float row_sum16(float v) {
  int x;
  x = __float_as_int(v);
  v += __int_as_float(__builtin_amdgcn_update_dpp(0, x, 0x128, 0xF, 0xF, true)); // row_ror:8
  x = __float_as_int(v);
  v += __int_as_float(__builtin_amdgcn_update_dpp(0, x, 0x124, 0xF, 0xF, true)); // row_ror:4
  x = __float_as_int(v);
  v += __int_as_float(__builtin_amdgcn_update_dpp(0, x, 0x04E, 0xF, 0xF, true)); // quad_perm xor2
  x = __float_as_int(v);
  v += __int_as_float(__builtin_amdgcn_update_dpp(0, x, 0x0B1, 0xF, 0xF, true)); // quad_perm xor1
  return v;
}

// ---------------- prep: normalize x rows, convert to padded bf16 ----------
__global__ __launch_bounds__(256) void prep_x(const float* __restrict__ x,
                                              unsigned short* __restrict__ xnb) {
  const int row  = blockIdx.x * 4 + (threadIdx.x >> 6);
  const int lane = threadIdx.x & 63;
  const float* xr = x + (size_t)row * D;
  float v0 = xr[lane], v1 = xr[lane + 64], v2 = xr[lane + 128];
  float ss = v0 * v0 + v1 * v1 + v2 * v2;
#pragma unroll
  for (int off = 32; off > 0; off >>= 1) ss += __shfl_xor(ss, off, 64);
  const float inv = rsqrtf(ss);
  unsigned short* o = xnb + (size_t)row * KP;
  o[lane]       = f2bf(v0 * inv);
  o[lane + 64]  = f2bf(v1 * inv);
  o[lane + 128] = f2bf(v2 * inv);
  if (lane < KP - D) o[D + lane] = 0;
}

// ---------------- main fused GEMM + exp-rowsum ----------------------------
// grid = (CT, 4); block = 256 (4 waves, 2x2 quadrants of 64x64).
// Each block: stage 128-class B tile once, loop RB=4 row-blocks of A.
__global__ __launch_bounds__(256, 3) void gemm_lse(
    const unsigned short* __restrict__ xnb,  // [N][KP] bf16
    const float* __restrict__ Wf,            // [C][D] fp32
    float* __restrict__ partial) {           // [N][PCP] fp32
  __shared__ alignas(16) unsigned short Bs[128 * KP];  // 51.2 KB

  const int tid    = threadIdx.x;
  const int colblk = blockIdx.x;
  const int ybase  = blockIdx.y;             // 0..3 (512-row band)

  // ---- stage B tile once: fp32 W -> bf16 LDS, coalesced float4 loads ----
  {
    const int cbase = colblk * 128;
#pragma unroll
    for (int i = 0; i < 24; ++i) {           // 6144 float4 = 128 rows x 48
      const int g   = tid + i * 256;
      const int row = g / 48;
      const int k4  = (g - row * 48) * 4;    // float offset within row
      const int rg  = cbase + row;
      float4 f = (rg < C) ? ((const float4*)(Wf + (size_t)rg * D))[k4 >> 2]
                          : make_float4(0.f, 0.f, 0.f, 0.f);
      ushort4 h;
      h.x = f2bf(f.x); h.y = f2bf(f.y); h.z = f2bf(f.z); h.w = f2bf(f.w);
      *(ushort4*)(&Bs[row * KP + k4]) = h;
    }
    // zero the K padding region [192,200)
    const int pr = tid >> 1, ph = (tid & 1) * 4;
    *(ushort4*)(&Bs[pr * KP + D + ph]) = make_ushort4(0, 0, 0, 0);
  }
  __syncthreads();  // the ONLY barrier in this kernel

  const int lane = tid & 63;
  const int wave = tid >> 6;
  const int m    = lane & 15;   // A row / B col within 16-tile
  const int quad = lane >> 4;   // k base = quad*8; C/D row base = quad*4
  const int wr   = wave >> 1;   // row half (64) of the 128x128 tile
  const int wc   = wave & 1;    // col half (64)

  const unsigned short* bbase = &Bs[(wc * 64 + m) * KP + quad * 8];
  const int colbase = colblk * 128 + wc * 64 + m;
  const int slot    = 2 * colblk + wc;       // this wave-pair's partial column
  const f32x4 zero4 = {0.0f, 0.0f, 0.0f, 0.0f};

  for (int rb = 0; rb < RB; ++rb) {
    const int rowg = ybase * (128 * RB) + rb * 128 + wr * 64;
    const unsigned short* abase = xnb + (size_t)(rowg + m) * KP + quad * 8;

    f32x4 acc[4][4];
#pragma unroll
    for (int a = 0; a < 4; ++a)
#pragma unroll
      for (int b = 0; b < 4; ++b) acc[a][b] = zero4;

#pragma unroll
    for (int ks = 0; ks < 6; ++ks) {  // K = 6 * 32
      short8 af[4], bf[4];
#pragma unroll
      for (int t = 0; t < 4; ++t)
        af[t] = *(const short8*)(abase + t * 16 * KP + ks * 32);
#pragma unroll
      for (int t = 0; t < 4; ++t)
        bf[t] = *(const short8*)(bbase + t * 16 * KP + ks * 32);
#pragma unroll
      for (int tr = 0; tr < 4; ++tr)
#pragma unroll
        for (int tc = 0; tc < 4; ++tc)
          acc[tr][tc] = __builtin_amdgcn_mfma_f32_16x16x32_bf16(
              af[tr], bf[tc], acc[tr][tc], 0, 0, 0);
    }

    // Epilogue: exp(S*wf), mask phantom cols, DPP 16-lane reduce, ONE plain
    // store per (row, slot) — contention-free by construction.
#pragma unroll
    for (int tr = 0; tr < 4; ++tr) {
      float r0 = 0.f, r1 = 0.f, r2 = 0.f, r3 = 0.f;
#pragma unroll
      for (int tc = 0; tc < 4; ++tc) {
        if (colbase + tc * 16 < C) {
          r0 += __expf(S_SCALE * acc[tr][tc][0]);
          r1 += __expf(S_SCALE * acc[tr][tc][1]);
          r2 += __expf(S_SCALE * acc[tr][tc][2]);
          r3 += __expf(S_SCALE * acc[tr][tc][3]);
        }
      }
      r0 = row_sum16(r0);
      r1 = row_sum16(r1);
      r2 = row_sum16(r2);
      r3 = row_sum16(r3);
      if (m == 0) {
        const size_t rg = (size_t)(rowg + tr * 16 + quad * 4);
        partial[(rg + 0) * PCP + slot] = r0;
        partial[(rg + 1) * PCP + slot] = r1;
        partial[(rg + 2) * PCP + slot] = r2;
        partial[(rg + 3) * PCP + slot] = r3;
      }
    }
  }
}

// ---------------- reduce partials -> sumexp[row] --------------------------
// One wave per row; 1564 contiguous floats = 391 float4.
__global__ __launch_bounds__(256) void reduce_partial(
    const float* __restrict__ partial, float* __restrict__ sumexp) {
  const int row  = blockIdx.x * 4 + (threadIdx.x >> 6);
  const int lane = threadIdx.x & 63;
  const float4* p = (const float4*)(partial + (size_t)row * PCP);
  float s = 0.0f;
#pragma unroll
  for (int i = 0; i < 7; ++i) {
    const int idx = lane + i * 64;
    if (idx < PC / 4) {
      float4 v = p[idx];
      s += (v.x + v.y) + (v.z + v.w);
    }
  }
#pragma unroll
  for (int off = 32; off > 0; off >>= 1) s += __shfl_xor(s, off, 64);
  if (lane == 0) sumexp[row] = s;
}

// ---------------- per-row finalize ---------------------------------------
__global__ __launch_bounds__(256) void finalize_rows(
    const float* __restrict__ x, const float* __restrict__ W,
    const int* __restrict__ label, const float* __restrict__ sumexp,
    float* __restrict__ Lrow) {
  const int row  = blockIdx.x * 4 + (threadIdx.x >> 6);
  const int lane = threadIdx.x & 63;
  const float* xr = x + (size_t)row * D;
  float v0 = xr[lane], v1 = xr[lane + 64], v2 = xr[lane + 128];
  float ss = v0 * v0 + v1 * v1 + v2 * v2;
  const int lab = label[row];
  const float* wr = W + (size_t)lab * D;
  float d = v0 * wr[lane] + v1 * wr[lane + 64] + v2 * wr[lane + 128];
#pragma unroll
  for (int off = 32; off > 0; off >>= 1) {
    ss += __shfl_xor(ss, off, 64);
    d  += __shfl_xor(d,  off, 64);
  }
  if (lane == 0) {
    const float tgt   = d * rsqrtf(ss);
    const float numer = S_SCALE * (tgt - MARGIN);
    // swap label column: remove its plain-logit exp, add margin-adjusted exp
    const float se = sumexp[row] - __expf(S_SCALE * tgt) + __expf(numer);
    Lrow[row] = numer - logf(se);
  }
}

__global__ __launch_bounds__(256) void reduce_loss(const float* __restrict__ Lrow,
                                                   float* __restrict__ out) {
  const int tid = threadIdx.x;
  float s = 0.0f;
  for (int i = tid; i < N; i += 256) s += Lrow[i];
#pragma unroll
  for (int off = 32; off > 0; off >>= 1) s += __shfl_xor(s, off, 64);
  __shared__ float part[4];
  if ((tid & 63) == 0) part[tid >> 6] = s;
  __syncthreads();
  if (tid == 0) out[0] = -(part[0] + part[1] + part[2] + part[3]) / (float)N;
}

// ---------------- host ----------------------------------------------------
extern "C" void kernel_launch(void* const* d_in, const int* in_sizes, int n_in,
                              void* d_out, int out_size, void* d_ws, size_t ws_size,
                              hipStream_t stream) {
  const float* x     = (const float*)d_in[0];
  const float* W     = (const float*)d_in[1];
  const int*   label = (const int*)d_in[2];
  float*       out   = (float*)d_out;

  char* ws = (char*)d_ws;
  size_t off = 0;
  unsigned short* xnb = (unsigned short*)(ws + off); off += (size_t)N * KP * 2;
  float* partial = (float*)(ws + off); off += (size_t)N * PCP * 4;   // 12.85 MB
  float* sumexp  = (float*)(ws + off); off += (size_t)N * 4;
  float* Lrow    = (float*)(ws + off);

  prep_x<<<N / 4, 256, 0, stream>>>(x, xnb);

  dim3 grid(CT, 4);
  gemm_lse<<<grid, 256, 0, stream>>>(xnb, W, partial);

  reduce_partial<<<N / 4, 256, 0, stream>>>(partial, sumexp);
  finalize_rows<<<N / 4, 256, 0, stream>>>(x, W, label, sumexp, Lrow);
  reduce_loss<<<1, 256, 0, stream>>>(Lrow, out);
}

// Round 4
// 286.260 us; speedup vs baseline: 2.1139x; 1.2779x over previous
//
#include <hip/hip_runtime.h>
#include <stdint.h>

// AM-softmax loss, fused on MI355X (gfx950) — round 4.
//
// vs round 3: A-operand feed moved from L2 (~56 B/cyc/CU cap -> 25% MFMA
// ceiling, the measured 11.5% MfmaUtil) into LDS. xnb is pre-packed in MFMA
// fragment order by prep_x, so each 128-row A-slab is a contiguous 48 KB
// image staged by global_load_lds dwordx4 into a double buffer (prefetch
// issued before compute; the __syncthreads vmcnt drain hits a completed DMA).
// B-tile (128 classes) is fragment-packed in LDS, staged once per block from
// fp32 W. All ds_read_b128 are uniform+lane*16 -> conflict-free. Partial
// exp-sums combined across the 4 col-waves in LDS each rb, stored once as a
// block-exclusive contiguous column partial[colblk][row] (no false sharing;
// round 3's 177 MB write amplification -> ~8 MB).

constexpr int N  = 2048;
constexpr int D  = 192;   // K
constexpr int C  = 100000;
constexpr int CT = (C + 127) / 128;   // 782 column tiles
constexpr int RB = 8;                 // row-blocks per block (grid.y = 2)
constexpr int KT = D / 32;            // 6 k-tiles of 32
constexpr int TILE_ELEMS = 512;       // one 16x32 fragment tile = 64 lanes x 8 bf16
constexpr int SLAB = 128 * D;         // 24576 ushort = 48 KB (8 row-tiles x 6 k-tiles)

#define S_SCALE 30.0f
#define MARGIN  0.2f

using short8 = __attribute__((ext_vector_type(8))) short;   // 8 bf16 (4 VGPRs)
using f32x4  = __attribute__((ext_vector_type(4))) float;   // MFMA C/D

typedef __attribute__((address_space(1))) const void GV;
typedef __attribute__((address_space(3))) void LV;

__device__ inline unsigned short f2bf(float f) {  // fp32 -> bf16 RNE
  unsigned int u = __float_as_uint(f);
  u += 0x7fffu + ((u >> 16) & 1u);
  return (unsigned short)(u >> 16);
}

// packed fragment index (in ushort units) for element (row r, k) of a
// row-tile-major matrix: tile (r>>4, k>>5), lane = (r&15) | ((k>>3)&3)<<4.
__device__ inline int pack_idx(int r, int k) {
  return ((r >> 4) * KT + (k >> 5)) * TILE_ELEMS + (((k >> 3) & 3) * 16 + (r & 15)) * 8 + (k & 7);
}

// Sum across each 16-lane DPP row; result valid in all 16 lanes.
__device__ inline float row_sum16(float v) {
  int x;
  x = __float_as_int(v);
  v += __int_as_float(__builtin_amdgcn_update_dpp(0, x, 0x128, 0xF, 0xF, true)); // row_ror:8
  x = __float_as_int(v);
  v += __int_as_float(__builtin_amdgcn_update_dpp(0, x, 0x124, 0xF, 0xF, true)); // row_ror:4
  x = __float_as_int(v);
  v += __int_as_float(__builtin_amdgcn_update_dpp(0, x, 0x04E, 0xF, 0xF, true)); // quad_perm xor2
  x = __float_as_int(v);
  v += __int_as_float(__builtin_amdgcn_update_dpp(0, x, 0x0B1, 0xF, 0xF, true)); // quad_perm xor1
  return v;
}

// ---------------- prep: normalize x rows -> packed bf16 fragments ---------
__global__ __launch_bounds__(256) void prep_x(const float* __restrict__ x,
                                              unsigned short* __restrict__ xnb) {
  const int row  = blockIdx.x * 4 + (threadIdx.x >> 6);
  const int lane = threadIdx.x & 63;
  const float* xr = x + (size_t)row * D;
  float v0 = xr[lane], v1 = xr[lane + 64], v2 = xr[lane + 128];
  float ss = v0 * v0 + v1 * v1 + v2 * v2;
#pragma unroll
  for (int off = 32; off > 0; off >>= 1) ss += __shfl_xor(ss, off, 64);
  const float inv = rsqrtf(ss);
  xnb[pack_idx(row, lane)]       = f2bf(v0 * inv);
  xnb[pack_idx(row, lane + 64)]  = f2bf(v1 * inv);
  xnb[pack_idx(row, lane + 128)] = f2bf(v2 * inv);
}

// ---------------- main fused GEMM + exp-rowsum ----------------------------
// grid = (CT, 2); block = 512 (8 waves: wr in {0,1} x wc in {0..3}).
// Wave tile: 64 rows x 32 cols (acc 4x2). B stationary; A double-buffered.
__global__ __launch_bounds__(512, 2) void gemm_lse(
    const unsigned short* __restrict__ xnb,  // packed [128 row-tiles][6 k-tiles][512]
    const float* __restrict__ Wf,            // [C][D] fp32
    float* __restrict__ partial) {           // [CT][N] fp32
  __shared__ alignas(16) unsigned short Bs[SLAB];       // 48 KB
  __shared__ alignas(16) unsigned short As[2 * SLAB];   // 96 KB (double buffer)
  __shared__ alignas(16) float rowsum[4 * 128];         // 2 KB (per-wc partial rows)

  const int tid    = threadIdx.x;
  const int colblk = blockIdx.x;
  const int ybase  = blockIdx.y;             // 0/1: 1024-row half

  // ---- issue DMA for A slab 0 (prefetch across the B-stage) ----
  const unsigned short* slab0 = xnb + (size_t)(ybase * 8) * KT * TILE_ELEMS * 8;
  {
#pragma unroll
    for (int i = 0; i < 6; ++i) {
      const int chunk = tid + i * 512;       // 3072 x 16 B = 48 KB
      __builtin_amdgcn_global_load_lds(
          (GV*)((const char*)slab0 + (size_t)chunk * 16),
          (LV*)((char*)As + (size_t)chunk * 16), 16, 0, 0);
    }
  }

  // ---- stage B tile once: fp32 W -> packed bf16 fragments in LDS ----
  {
    const int cbase = colblk * 128;
#pragma unroll
    for (int i = 0; i < 6; ++i) {            // 3072 chunks: (col, 8 k)
      const int g   = tid + i * 512;
      const int col = g / 24;                // local col 0..127
      const int kc  = g - col * 24;          // k-chunk of 8 (0..23)
      const int gc  = cbase + col;
      short8 hv;
      if (gc < C) {
        const float4* src = (const float4*)(Wf + (size_t)gc * D + kc * 8);
        float4 f0 = src[0], f1 = src[1];
        hv[0] = (short)f2bf(f0.x); hv[1] = (short)f2bf(f0.y);
        hv[2] = (short)f2bf(f0.z); hv[3] = (short)f2bf(f0.w);
        hv[4] = (short)f2bf(f1.x); hv[5] = (short)f2bf(f1.y);
        hv[6] = (short)f2bf(f1.z); hv[7] = (short)f2bf(f1.w);
      } else {
        hv = short8{0, 0, 0, 0, 0, 0, 0, 0};
      }
      const int s = kc >> 2, q = kc & 3;
      const int idx = ((col >> 4) * KT + s) * TILE_ELEMS + (q * 16 + (col & 15)) * 8;
      *(short8*)(&Bs[idx]) = hv;
    }
  }
  __syncthreads();  // drains B ds_writes AND slab-0 DMA (vmcnt 0)

  const int lane = tid & 63;
  const int wave = tid >> 6;
  const int m    = lane & 15;   // A row / B col within 16-tile
  const int quad = lane >> 4;
  const int wr   = wave >> 2;   // 0/1: 64-row half of the 128-row slab
  const int wc   = wave & 3;    // 0..3: 32-col group

  const f32x4 zero4 = {0.0f, 0.0f, 0.0f, 0.0f};

  for (int rb = 0; rb < RB; ++rb) {
    // prefetch next A slab into the other buffer (issued before compute;
    // by the time __syncthreads drains vmcnt it is long complete)
    if (rb + 1 < RB) {
      const unsigned short* slab =
          xnb + (size_t)((ybase * 8 + rb + 1) * 8) * KT * TILE_ELEMS;
      char* dst = (char*)&As[((rb + 1) & 1) * SLAB];
#pragma unroll
      for (int i = 0; i < 6; ++i) {
        const int chunk = tid + i * 512;
        __builtin_amdgcn_global_load_lds(
            (GV*)((const char*)slab + (size_t)chunk * 16),
            (LV*)(dst + (size_t)chunk * 16), 16, 0, 0);
      }
    }

    const unsigned short* Asb = &As[(rb & 1) * SLAB];

    f32x4 acc[4][2];
#pragma unroll
    for (int a = 0; a < 4; ++a)
#pragma unroll
      for (int b = 0; b < 2; ++b) acc[a][b] = zero4;

#pragma unroll
    for (int ks = 0; ks < KT; ++ks) {
      short8 af[4], bf[2];
#pragma unroll
      for (int tr = 0; tr < 4; ++tr)
        af[tr] = *(const short8*)(&Asb[((wr * 4 + tr) * KT + ks) * TILE_ELEMS + lane * 8]);
#pragma unroll
      for (int tc = 0; tc < 2; ++tc)
        bf[tc] = *(const short8*)(&Bs[((wc * 2 + tc) * KT + ks) * TILE_ELEMS + lane * 8]);
#pragma unroll
      for (int tr = 0; tr < 4; ++tr)
#pragma unroll
        for (int tc = 0; tc < 2; ++tc)
          acc[tr][tc] = __builtin_amdgcn_mfma_f32_16x16x32_bf16(
              af[tr], bf[tc], acc[tr][tc], 0, 0, 0);
    }

    // Epilogue: exp(S*wf), mask phantom cols, DPP 16-lane reduce, combine the
    // 4 wc-waves through LDS, one coalesced store per 128-row chunk.
#pragma unroll
    for (int tr = 0; tr < 4; ++tr) {
      float r0 = 0.f, r1 = 0.f, r2 = 0.f, r3 = 0.f;
#pragma unroll
      for (int tc = 0; tc < 2; ++tc) {
        const int gcol = colblk * 128 + (wc * 2 + tc) * 16 + m;
        if (gcol < C) {
          r0 += __expf(S_SCALE * acc[tr][tc][0]);
          r1 += __expf(S_SCALE * acc[tr][tc][1]);
          r2 += __expf(S_SCALE * acc[tr][tc][2]);
          r3 += __expf(S_SCALE * acc[tr][tc][3]);
        }
      }
      r0 = row_sum16(r0);
      r1 = row_sum16(r1);
      r2 = row_sum16(r2);
      r3 = row_sum16(r3);
      if (m == 0) {
        float4 v = make_float4(r0, r1, r2, r3);
        *(float4*)(&rowsum[wc * 128 + wr * 64 + tr * 16 + quad * 4]) = v;
      }
    }
    __syncthreads();  // rowsum complete; everyone done with As[rb&1]; DMA drained
    if (tid < 128) {
      const float s = rowsum[tid] + rowsum[128 + tid] + rowsum[256 + tid] + rowsum[384 + tid];
      partial[(size_t)colblk * N + ybase * 1024 + rb * 128 + tid] = s;
    }
    __syncthreads();  // rowsum free for next rb
  }
}

// ---------------- reduce partials -> sumexp[row] --------------------------
// grid (8, 8): 256 rows x ~98-slot chunk per block; atomicAdd per row-chunk.
__global__ __launch_bounds__(256) void reduce_partial(
    const float* __restrict__ partial, float* __restrict__ sumexp) {
  const int row = blockIdx.x * 256 + threadIdx.x;
  const int s0  = blockIdx.y * 98;
  float acc = 0.0f;
  for (int i = 0; i < 98; ++i) {
    const int slot = s0 + i;
    if (slot < CT) acc += partial[(size_t)slot * N + row];
  }
  atomicAdd(&sumexp[row], acc);
}

// ---------------- per-row finalize ---------------------------------------
__global__ __launch_bounds__(256) void finalize_rows(
    const float* __restrict__ x, const float* __restrict__ W,
    const int* __restrict__ label, const float* __restrict__ sumexp,
    float* __restrict__ Lrow) {
  const int row  = blockIdx.x * 4 + (threadIdx.x >> 6);
  const int lane = threadIdx.x & 63;
  const float* xr = x + (size_t)row * D;
  float v0 = xr[lane], v1 = xr[lane + 64], v2 = xr[lane + 128];
  float ss = v0 * v0 + v1 * v1 + v2 * v2;
  const int lab = label[row];
  const float* wr = W + (size_t)lab * D;
  float d = v0 * wr[lane] + v1 * wr[lane + 64] + v2 * wr[lane + 128];
#pragma unroll
  for (int off = 32; off > 0; off >>= 1) {
    ss += __shfl_xor(ss, off, 64);
    d  += __shfl_xor(d,  off, 64);
  }
  if (lane == 0) {
    const float tgt   = d * rsqrtf(ss);
    const float numer = S_SCALE * (tgt - MARGIN);
    // swap label column: remove its plain-logit exp, add margin-adjusted exp
    const float se = sumexp[row] - __expf(S_SCALE * tgt) + __expf(numer);
    Lrow[row] = numer - logf(se);
  }
}

__global__ __launch_bounds__(256) void reduce_loss(const float* __restrict__ Lrow,
                                                   float* __restrict__ out) {
  const int tid = threadIdx.x;
  float s = 0.0f;
  for (int i = tid; i < N; i += 256) s += Lrow[i];
#pragma unroll
  for (int off = 32; off > 0; off >>= 1) s += __shfl_xor(s, off, 64);
  __shared__ float part[4];
  if ((tid & 63) == 0) part[tid >> 6] = s;
  __syncthreads();
  if (tid == 0) out[0] = -(part[0] + part[1] + part[2] + part[3]) / (float)N;
}

// ---------------- host ----------------------------------------------------
extern "C" void kernel_launch(void* const* d_in, const int* in_sizes, int n_in,
                              void* d_out, int out_size, void* d_ws, size_t ws_size,
                              hipStream_t stream) {
  const float* x     = (const float*)d_in[0];
  const float* W     = (const float*)d_in[1];
  const int*   label = (const int*)d_in[2];
  float*       out   = (float*)d_out;

  char* ws = (char*)d_ws;
  size_t off = 0;
  unsigned short* xnb = (unsigned short*)(ws + off); off += (size_t)N * D * 2;      // 768 KB
  float* partial = (float*)(ws + off); off += (size_t)CT * N * 4;                    // 6.4 MB
  float* sumexp  = (float*)(ws + off); off += (size_t)N * 4;
  float* Lrow    = (float*)(ws + off);

  hipMemsetAsync(sumexp, 0, N * sizeof(float), stream);
  prep_x<<<N / 4, 256, 0, stream>>>(x, xnb);

  dim3 grid(CT, 2);
  gemm_lse<<<grid, 512, 0, stream>>>(xnb, W, partial);

  dim3 rgrid(N / 256, 8);
  reduce_partial<<<rgrid, 256, 0, stream>>>(partial, sumexp);
  finalize_rows<<<N / 4, 256, 0, stream>>>(x, W, label, sumexp, Lrow);
  reduce_loss<<<1, 256, 0, stream>>>(Lrow, out);
}

// Round 5
// 284.827 us; speedup vs baseline: 2.1246x; 1.0050x over previous
//
#include <hip/hip_runtime.h>
#include <stdint.h>

// AM-softmax loss, fused on MI355X (gfx950) — round 5.
//
// vs round 4 (175 us gemm, MfmaUtil 18.6, VALU 34.8 — pipes serialized by
// per-rb barrier lockstep):
//  * 4x4 acc blocking (64x64 wave tile; 8 waves = 4wr x 2wc over a
//    256-row x 128-col block tile): LDS 768 -> 512 B/MFMA, DPP cost /4.
//  * xn pre-scaled by S*log2(e) -> epilogue is raw v_exp_f32 (exp2), no mul.
//  * per-wave partial stores to wave-exclusive slots (no cross-wave rowsum
//    combine, one barrier pair per rb only for the A-slab swap).
//  * A: single-buffered 256-row slab (96 KB) via global_load_lds dwordx4;
//    B: 128-class fragment-packed tile (48 KB) staged once. LDS 144 KB.

constexpr int N  = 2048;
constexpr int D  = 192;   // K
constexpr int C  = 100000;
constexpr int CT = (C + 127) / 128;   // 782 column tiles
constexpr int KT = D / 32;            // 6 k-tiles of 32
constexpr int TILE_ELEMS = 512;       // one 16x32 fragment tile (64 lanes x 8 bf16)
constexpr int RB = 8;                 // 8 slabs of 256 rows
constexpr int PC = 2 * CT;            // 1564 partial slots

#define S_SCALE 30.0f
#define MARGIN  0.2f
#define S_LOG2E 43.2808512266689f     // 30 * log2(e)

using short8 = __attribute__((ext_vector_type(8))) short;   // 8 bf16 (4 VGPRs)
using f32x4  = __attribute__((ext_vector_type(4))) float;   // MFMA C/D

typedef __attribute__((address_space(1))) const void GV;
typedef __attribute__((address_space(3))) void LV;

__device__ inline unsigned short f2bf(float f) {  // fp32 -> bf16 RNE
  unsigned int u = __float_as_uint(f);
  u += 0x7fffu + ((u >> 16) & 1u);
  return (unsigned short)(u >> 16);
}

// packed fragment index (ushort units) for element (row r, k):
// tile (r>>4, k>>5), lane = (r&15) + ((k>>3)&3)*16, elem k&7.
__device__ inline int pack_idx(int r, int k) {
  return ((r >> 4) * KT + (k >> 5)) * TILE_ELEMS + (((k >> 3) & 3) * 16 + (r & 15)) * 8 + (k & 7);
}

// Sum across each 16-lane DPP row; result valid in all 16 lanes.
__device__ inline float row_sum16(float v) {
  int x;
  x = __float_as_int(v);
  v += __int_as_float(__builtin_amdgcn_update_dpp(0, x, 0x128, 0xF, 0xF, true)); // row_ror:8
  x = __float_as_int(v);
  v += __int_as_float(__builtin_amdgcn_update_dpp(0, x, 0x124, 0xF, 0xF, true)); // row_ror:4
  x = __float_as_int(v);
  v += __int_as_float(__builtin_amdgcn_update_dpp(0, x, 0x04E, 0xF, 0xF, true)); // quad_perm xor2
  x = __float_as_int(v);
  v += __int_as_float(__builtin_amdgcn_update_dpp(0, x, 0x0B1, 0xF, 0xF, true)); // quad_perm xor1
  return v;
}

// ---------------- prep: normalize x rows -> packed bf16 * S*log2e ---------
__global__ __launch_bounds__(256) void prep_x(const float* __restrict__ x,
                                              unsigned short* __restrict__ xnb) {
  const int row  = blockIdx.x * 4 + (threadIdx.x >> 6);
  const int lane = threadIdx.x & 63;
  const float* xr = x + (size_t)row * D;
  float v0 = xr[lane], v1 = xr[lane + 64], v2 = xr[lane + 128];
  float ss = v0 * v0 + v1 * v1 + v2 * v2;
#pragma unroll
  for (int off = 32; off > 0; off >>= 1) ss += __shfl_xor(ss, off, 64);
  const float inv = rsqrtf(ss) * S_LOG2E;   // fold exp scale into A
  xnb[pack_idx(row, lane)]       = f2bf(v0 * inv);
  xnb[pack_idx(row, lane + 64)]  = f2bf(v1 * inv);
  xnb[pack_idx(row, lane + 128)] = f2bf(v2 * inv);
}

// ---------------- main fused GEMM + exp-rowsum ----------------------------
// grid = (CT); block = 512 (8 waves: wr 0..3 x wc 0..1), wave tile 64x64.
// Block tile per rb: 256 rows x 128 cols; RB=8 covers all 2048 rows.
__global__ __launch_bounds__(512, 2) void gemm_lse(
    const unsigned short* __restrict__ xnb,  // packed [128 row-tiles][KT][512]
    const float* __restrict__ Wf,            // [C][D] fp32
    float* __restrict__ partial) {           // [PC][N] fp32
  __shared__ alignas(16) unsigned short Bs[8 * KT * TILE_ELEMS];    // 48 KB
  __shared__ alignas(16) unsigned short As[16 * KT * TILE_ELEMS];   // 96 KB

  const int tid    = threadIdx.x;
  const int colblk = blockIdx.x;

  // ---- stage B tile once: fp32 W -> packed bf16 fragments in LDS ----
  {
    const int cbase = colblk * 128;
#pragma unroll
    for (int i = 0; i < 6; ++i) {            // 3072 chunks: (col, 8 k)
      const int g   = tid + i * 512;
      const int col = g / 24;                // local col 0..127
      const int kc  = g - col * 24;          // k-chunk of 8 (0..23)
      const int gc  = cbase + col;
      short8 hv;
      if (gc < C) {
        const float4* src = (const float4*)(Wf + (size_t)gc * D + kc * 8);
        float4 f0 = src[0], f1 = src[1];
        hv[0] = (short)f2bf(f0.x); hv[1] = (short)f2bf(f0.y);
        hv[2] = (short)f2bf(f0.z); hv[3] = (short)f2bf(f0.w);
        hv[4] = (short)f2bf(f1.x); hv[5] = (short)f2bf(f1.y);
        hv[6] = (short)f2bf(f1.z); hv[7] = (short)f2bf(f1.w);
      } else {
        hv = short8{0, 0, 0, 0, 0, 0, 0, 0};
      }
      const int s = kc >> 2, q = kc & 3;
      const int idx = ((col >> 4) * KT + s) * TILE_ELEMS + (q * 16 + (col & 15)) * 8;
      *(short8*)(&Bs[idx]) = hv;
    }
  }

  const int lane = tid & 63;
  const int wave = tid >> 6;
  const int m    = lane & 15;   // A row / B col within 16-tile
  const int quad = lane >> 4;   // C/D row base = quad*4
  const int wr   = wave >> 1;   // 0..3: 64-row group of the 256-row slab
  const int wc   = wave & 1;    // 0..1: 64-col half

  const int colbase = colblk * 128 + wc * 64 + m;
  const int slot    = 2 * colblk + wc;       // wave-exclusive partial column
  const f32x4 zero4 = {0.0f, 0.0f, 0.0f, 0.0f};

  for (int rb = 0; rb < RB; ++rb) {
    __syncthreads();   // all waves done reading As from previous rb
    // ---- DMA 256-row A slab (96 KB contiguous, fragment-packed) ----
    const unsigned short* slab = xnb + (size_t)(rb * 16) * KT * TILE_ELEMS;
#pragma unroll
    for (int i = 0; i < 12; ++i) {           // 6144 x 16 B
      const int chunk = tid + i * 512;
      __builtin_amdgcn_global_load_lds(
          (GV*)((const char*)slab + (size_t)chunk * 16),
          (LV*)((char*)As + (size_t)chunk * 16), 16, 0, 0);
    }
    __syncthreads();   // vmcnt drain: slab ready (and B on rb==0)

    f32x4 acc[4][4];
#pragma unroll
    for (int a = 0; a < 4; ++a)
#pragma unroll
      for (int b = 0; b < 4; ++b) acc[a][b] = zero4;

#pragma unroll
    for (int ks = 0; ks < KT; ++ks) {
      short8 af[4], bf[4];
#pragma unroll
      for (int tr = 0; tr < 4; ++tr)
        af[tr] = *(const short8*)(&As[((wr * 4 + tr) * KT + ks) * TILE_ELEMS + lane * 8]);
#pragma unroll
      for (int tc = 0; tc < 4; ++tc)
        bf[tc] = *(const short8*)(&Bs[((wc * 4 + tc) * KT + ks) * TILE_ELEMS + lane * 8]);
#pragma unroll
      for (int tr = 0; tr < 4; ++tr)
#pragma unroll
        for (int tc = 0; tc < 4; ++tc)
          acc[tr][tc] = __builtin_amdgcn_mfma_f32_16x16x32_bf16(
              af[tr], bf[tc], acc[tr][tc], 0, 0, 0);
    }

    // ---- epilogue: exp2 (arg pre-scaled), col mask, DPP reduce, store ----
    const int rowg = rb * 256 + wr * 64;
#pragma unroll
    for (int tr = 0; tr < 4; ++tr) {
      float rv0 = 0.f, rv1 = 0.f, rv2 = 0.f, rv3 = 0.f;
#pragma unroll
      for (int tc = 0; tc < 4; ++tc) {
        const bool ok = (colbase + tc * 16) < C;   // per-lane (m) guard
        float e0 = __builtin_amdgcn_exp2f(acc[tr][tc][0]);
        float e1 = __builtin_amdgcn_exp2f(acc[tr][tc][1]);
        float e2 = __builtin_amdgcn_exp2f(acc[tr][tc][2]);
        float e3 = __builtin_amdgcn_exp2f(acc[tr][tc][3]);
        rv0 += ok ? e0 : 0.f;
        rv1 += ok ? e1 : 0.f;
        rv2 += ok ? e2 : 0.f;
        rv3 += ok ? e3 : 0.f;
      }
      rv0 = row_sum16(rv0);
      rv1 = row_sum16(rv1);
      rv2 = row_sum16(rv2);
      rv3 = row_sum16(rv3);
      if (m == 0) {
        float4 v = make_float4(rv0, rv1, rv2, rv3);  // rows +0..+3 of quad*4
        *(float4*)(&partial[(size_t)slot * N + rowg + tr * 16 + quad * 4]) = v;
      }
    }
  }
}

// ---------------- reduce partials -> sumexp[row] --------------------------
// grid (N/256, 8); each block: 256 rows x 196-slot chunk, coalesced reads.
__global__ __launch_bounds__(256) void reduce_partial(
    const float* __restrict__ partial, float* __restrict__ sumexp) {
  const int row = blockIdx.x * 256 + threadIdx.x;
  const int s0  = blockIdx.y * 196;
  float acc = 0.0f;
  for (int i = 0; i < 196; ++i) {
    const int slot = s0 + i;
    if (slot < PC) acc += partial[(size_t)slot * N + row];
  }
  atomicAdd(&sumexp[row], acc);
}

// ---------------- per-row finalize ---------------------------------------
__global__ __launch_bounds__(256) void finalize_rows(
    const float* __restrict__ x, const float* __restrict__ W,
    const int* __restrict__ label, const float* __restrict__ sumexp,
    float* __restrict__ Lrow) {
  const int row  = blockIdx.x * 4 + (threadIdx.x >> 6);
  const int lane = threadIdx.x & 63;
  const float* xr = x + (size_t)row * D;
  float v0 = xr[lane], v1 = xr[lane + 64], v2 = xr[lane + 128];
  float ss = v0 * v0 + v1 * v1 + v2 * v2;
  const int lab = label[row];
  const float* wr = W + (size_t)lab * D;
  float d = v0 * wr[lane] + v1 * wr[lane + 64] + v2 * wr[lane + 128];
#pragma unroll
  for (int off = 32; off > 0; off >>= 1) {
    ss += __shfl_xor(ss, off, 64);
    d  += __shfl_xor(d,  off, 64);
  }
  if (lane == 0) {
    const float tgt   = d * rsqrtf(ss);
    const float numer = S_SCALE * (tgt - MARGIN);
    // swap label column: remove its plain-logit exp, add margin-adjusted exp
    const float se = sumexp[row] - __expf(S_SCALE * tgt) + __expf(numer);
    Lrow[row] = numer - logf(se);
  }
}

__global__ __launch_bounds__(256) void reduce_loss(const float* __restrict__ Lrow,
                                                   float* __restrict__ out) {
  const int tid = threadIdx.x;
  float s = 0.0f;
  for (int i = tid; i < N; i += 256) s += Lrow[i];
#pragma unroll
  for (int off = 32; off > 0; off >>= 1) s += __shfl_xor(s, off, 64);
  __shared__ float part[4];
  if ((tid & 63) == 0) part[tid >> 6] = s;
  __syncthreads();
  if (tid == 0) out[0] = -(part[0] + part[1] + part[2] + part[3]) / (float)N;
}

// ---------------- host ----------------------------------------------------
extern "C" void kernel_launch(void* const* d_in, const int* in_sizes, int n_in,
                              void* d_out, int out_size, void* d_ws, size_t ws_size,
                              hipStream_t stream) {
  const float* x     = (const float*)d_in[0];
  const float* W     = (const float*)d_in[1];
  const int*   label = (const int*)d_in[2];
  float*       out   = (float*)d_out;

  char* ws = (char*)d_ws;
  size_t off = 0;
  unsigned short* xnb = (unsigned short*)(ws + off); off += (size_t)N * D * 2;  // 768 KB
  float* partial = (float*)(ws + off); off += (size_t)PC * N * 4;               // 12.8 MB
  float* sumexp  = (float*)(ws + off); off += (size_t)N * 4;
  float* Lrow    = (float*)(ws + off);

  hipMemsetAsync(sumexp, 0, N * sizeof(float), stream);
  prep_x<<<N / 4, 256, 0, stream>>>(x, xnb);

  gemm_lse<<<CT, 512, 0, stream>>>(xnb, W, partial);

  dim3 rgrid(N / 256, 8);
  reduce_partial<<<rgrid, 256, 0, stream>>>(partial, sumexp);
  finalize_rows<<<N / 4, 256, 0, stream>>>(x, W, label, sumexp, Lrow);
  reduce_loss<<<1, 256, 0, stream>>>(Lrow, out);
}

// Round 6
// 254.244 us; speedup vs baseline: 2.3801x; 1.1203x over previous
//
#include <hip/hip_runtime.h>
#include <stdint.h>

// AM-softmax loss, fused on MI355X (gfx950) — round 6.
//
// vs round 5 (146 us gemm; pipes ~MFMA 38 + LDS 50 + exp/VALU ~50 us fully
// SERIALIZED by per-rb barrier lockstep at 1 block/CU):
//  * barrier-free K-loop: block = 8 waves; A slab (256 rows, fragment-packed)
//    DMA'd to 96 KB LDS once (ONE barrier); each wave owns a private 64-col
//    tile whose B fragments are held in ~96 VGPRs, loaded once from a
//    pre-packed bf16 Wb (new prep_w) as coalesced 1 KB wave-loads.
//  * after the barrier, waves run independently: 4 rowsteps x (24 A ds_reads
//    + 96 MFMA + exp2 epilogue). LDS reads/MFMA halved (B reads eliminated).
//  * per-block rowsum combine in LDS -> partial[196][2048] (1.6 MB, no
//    atomics, coalesced); tiny reduce -> sumexp.

constexpr int N  = 2048;
constexpr int D  = 192;               // K
constexpr int C  = 100000;
constexpr int KT = D / 32;            // 6 k-tiles of 32
constexpr int TILE = 512;             // elems per 16x32 fragment tile
constexpr int RT16 = C / 16;          // 6250 real 16-col tiles (C % 16 == 0)
constexpr int CX = 196;               // col block groups
constexpr int RY = 8;                 // 256-row bands
constexpr int GT = CX * 8;            // 1568 64-col wave tiles
constexpr int NT16 = GT * 4;          // 6272 16-col tiles in Wb (incl. zero pads)

#define S_SCALE 30.0f
#define MARGIN  0.2f
#define S_LOG2E 43.2808512266689f     // 30 * log2(e)

using short8 = __attribute__((ext_vector_type(8))) short;   // 8 bf16 (4 VGPRs)
using f32x4  = __attribute__((ext_vector_type(4))) float;   // MFMA C/D

typedef __attribute__((address_space(1))) const void GV;
typedef __attribute__((address_space(3))) void LV;

__device__ inline unsigned short f2bf(float f) {  // fp32 -> bf16 RNE
  unsigned int u = __float_as_uint(f);
  u += 0x7fffu + ((u >> 16) & 1u);
  return (unsigned short)(u >> 16);
}

// packed fragment index (ushort units) for element (row r, k):
// tile (r>>4, k>>5), lane = (r&15) + ((k>>3)&3)*16, elem k&7.
__device__ inline int pack_idx(int r, int k) {
  return ((r >> 4) * KT + (k >> 5)) * TILE + (((k >> 3) & 3) * 16 + (r & 15)) * 8 + (k & 7);
}

// Sum across each 16-lane DPP row; result valid in all 16 lanes.
__device__ inline float row_sum16(float v) {
  int x;
  x = __float_as_int(v);
  v += __int_as_float(__builtin_amdgcn_update_dpp(0, x, 0x128, 0xF, 0xF, true)); // row_ror:8
  x = __float_as_int(v);
  v += __int_as_float(__builtin_amdgcn_update_dpp(0, x, 0x124, 0xF, 0xF, true)); // row_ror:4
  x = __float_as_int(v);
  v += __int_as_float(__builtin_amdgcn_update_dpp(0, x, 0x04E, 0xF, 0xF, true)); // quad_perm xor2
  x = __float_as_int(v);
  v += __int_as_float(__builtin_amdgcn_update_dpp(0, x, 0x0B1, 0xF, 0xF, true)); // quad_perm xor1
  return v;
}

// ---------------- prep: normalize x rows -> packed bf16 * S*log2e ---------
__global__ __launch_bounds__(256) void prep_x(const float* __restrict__ x,
                                              unsigned short* __restrict__ xnb) {
  const int row  = blockIdx.x * 4 + (threadIdx.x >> 6);
  const int lane = threadIdx.x & 63;
  const float* xr = x + (size_t)row * D;
  float v0 = xr[lane], v1 = xr[lane + 64], v2 = xr[lane + 128];
  float ss = v0 * v0 + v1 * v1 + v2 * v2;
#pragma unroll
  for (int off = 32; off > 0; off >>= 1) ss += __shfl_xor(ss, off, 64);
  const float inv = rsqrtf(ss) * S_LOG2E;   // fold exp scale into A
  xnb[pack_idx(row, lane)]       = f2bf(v0 * inv);
  xnb[pack_idx(row, lane + 64)]  = f2bf(v1 * inv);
  xnb[pack_idx(row, lane + 128)] = f2bf(v2 * inv);
}

// ---------------- prep: W fp32 -> fragment-packed bf16 Wb -----------------
// One wave per 16-col tile: Wb[t16][ks][lane*8 + e] holds
// W[t16*16 + (lane&15)][ks*32 + (lane>>4)*8 + e] as bf16. Tiles >= RT16 are
// zero (phantom classes; also masked in the gemm epilogue).
__global__ __launch_bounds__(256) void prep_w(const float* __restrict__ W,
                                              unsigned short* __restrict__ Wb) {
  const int t16  = blockIdx.x * 4 + (threadIdx.x >> 6);
  const int lane = threadIdx.x & 63;
  const int m = lane & 15, q = lane >> 4;
  unsigned short* dst = Wb + (size_t)t16 * KT * TILE + lane * 8;
  if (t16 < RT16) {
    const float* src = W + (size_t)(t16 * 16 + m) * D + q * 8;
#pragma unroll
    for (int ks = 0; ks < KT; ++ks) {
      const float4* s4 = (const float4*)(src + ks * 32);
      float4 f0 = s4[0], f1 = s4[1];
      short8 hv;
      hv[0] = (short)f2bf(f0.x); hv[1] = (short)f2bf(f0.y);
      hv[2] = (short)f2bf(f0.z); hv[3] = (short)f2bf(f0.w);
      hv[4] = (short)f2bf(f1.x); hv[5] = (short)f2bf(f1.y);
      hv[6] = (short)f2bf(f1.z); hv[7] = (short)f2bf(f1.w);
      *(short8*)(dst + (size_t)ks * TILE) = hv;
    }
  } else {
    const short8 z = {0, 0, 0, 0, 0, 0, 0, 0};
#pragma unroll
    for (int ks = 0; ks < KT; ++ks) *(short8*)(dst + (size_t)ks * TILE) = z;
  }
}

// ---------------- main fused GEMM + exp-rowsum ----------------------------
// grid = (CX, RY); block = 512 (8 waves). Wave w owns 64-col tile gt=cx*8+w
// (B in registers); all waves share the 256-row A slab in LDS. ONE barrier
// after staging; waves then run 4 independent rowsteps of 64 rows.
__global__ __launch_bounds__(512, 2) void gemm_lse(
    const unsigned short* __restrict__ xnb,  // packed [128 row-tiles][KT][512]
    const unsigned short* __restrict__ Wb,   // packed [NT16][KT][512]
    float* __restrict__ partial) {           // [CX][N]
  __shared__ alignas(16) unsigned short As[16 * KT * TILE];  // 96 KB
  __shared__ alignas(16) float rs_lds[8][256];               // 8 KB

  const int tid = threadIdx.x;
  const int cx = blockIdx.x, ry = blockIdx.y;

  // ---- DMA the 256-row A slab (96 KB contiguous, fragment-packed) ----
  const unsigned short* slab = xnb + (size_t)(ry * 16) * KT * TILE;
#pragma unroll
  for (int i = 0; i < 12; ++i) {             // 6144 x 16 B
    const int chunk = tid + i * 512;
    __builtin_amdgcn_global_load_lds(
        (GV*)((const char*)slab + (size_t)chunk * 16),
        (LV*)((char*)As + (size_t)chunk * 16), 16, 0, 0);
  }

  const int lane = tid & 63, wave = tid >> 6;
  const int m = lane & 15, quad = lane >> 4;
  const int gt = cx * 8 + wave;              // this wave's 64-col tile

  // ---- B fragments -> registers (24 coalesced 1 KB wave-loads) ----
  short8 breg[4][KT];
#pragma unroll
  for (int tc = 0; tc < 4; ++tc)
#pragma unroll
    for (int ks = 0; ks < KT; ++ks)
      breg[tc][ks] = *(const short8*)(
          Wb + (size_t)((gt * 4 + tc) * KT + ks) * TILE + lane * 8);

  bool okc[4];
#pragma unroll
  for (int tc = 0; tc < 4; ++tc) okc[tc] = (gt * 4 + tc) < RT16;

  __syncthreads();  // A slab ready (drains DMA); the ONLY pre-loop barrier

  const f32x4 zero4 = {0.0f, 0.0f, 0.0f, 0.0f};

  for (int rs = 0; rs < 4; ++rs) {           // 4 independent 64-row steps
    f32x4 acc[4][4];
#pragma unroll
    for (int a = 0; a < 4; ++a)
#pragma unroll
      for (int b = 0; b < 4; ++b) acc[a][b] = zero4;

#pragma unroll
    for (int ks = 0; ks < KT; ++ks) {
      short8 af[4];
#pragma unroll
      for (int tr = 0; tr < 4; ++tr)
        af[tr] = *(const short8*)(
            &As[((rs * 4 + tr) * KT + ks) * TILE + lane * 8]);
#pragma unroll
      for (int tr = 0; tr < 4; ++tr)
#pragma unroll
        for (int tc = 0; tc < 4; ++tc)
          acc[tr][tc] = __builtin_amdgcn_mfma_f32_16x16x32_bf16(
              af[tr], breg[tc][ks], acc[tr][tc], 0, 0, 0);
    }

    // ---- epilogue: exp2 (arg pre-scaled), phantom-col mask, DPP reduce ----
#pragma unroll
    for (int tr = 0; tr < 4; ++tr) {
      float rv0 = 0.f, rv1 = 0.f, rv2 = 0.f, rv3 = 0.f;
#pragma unroll
      for (int tc = 0; tc < 4; ++tc) {
        float e0 = __builtin_amdgcn_exp2f(acc[tr][tc][0]);
        float e1 = __builtin_amdgcn_exp2f(acc[tr][tc][1]);
        float e2 = __builtin_amdgcn_exp2f(acc[tr][tc][2]);
        float e3 = __builtin_amdgcn_exp2f(acc[tr][tc][3]);
        rv0 += okc[tc] ? e0 : 0.f;
        rv1 += okc[tc] ? e1 : 0.f;
        rv2 += okc[tc] ? e2 : 0.f;
        rv3 += okc[tc] ? e3 : 0.f;
      }
      rv0 = row_sum16(rv0);
      rv1 = row_sum16(rv1);
      rv2 = row_sum16(rv2);
      rv3 = row_sum16(rv3);
      if (m == 0) {
        float4 v = make_float4(rv0, rv1, rv2, rv3);
        *(float4*)(&rs_lds[wave][rs * 64 + tr * 16 + quad * 4]) = v;
      }
    }
  }

  __syncthreads();  // all waves' rowsums in LDS
  if (tid < 256) {
    float s = 0.0f;
#pragma unroll
    for (int w = 0; w < 8; ++w) s += rs_lds[w][tid];
    partial[(size_t)cx * N + ry * 256 + tid] = s;   // coalesced, exclusive
  }
}

// ---------------- reduce partials -> sumexp[row] --------------------------
__global__ __launch_bounds__(256) void reduce_partial(
    const float* __restrict__ partial, float* __restrict__ sumexp) {
  const int row = blockIdx.x * 256 + threadIdx.x;
  float acc = 0.0f;
  for (int s = 0; s < CX; ++s) acc += partial[(size_t)s * N + row];
  sumexp[row] = acc;
}

// ---------------- per-row finalize ---------------------------------------
__global__ __launch_bounds__(256) void finalize_rows(
    const float* __restrict__ x, const float* __restrict__ W,
    const int* __restrict__ label, const float* __restrict__ sumexp,
    float* __restrict__ Lrow) {
  const int row  = blockIdx.x * 4 + (threadIdx.x >> 6);
  const int lane = threadIdx.x & 63;
  const float* xr = x + (size_t)row * D;
  float v0 = xr[lane], v1 = xr[lane + 64], v2 = xr[lane + 128];
  float ss = v0 * v0 + v1 * v1 + v2 * v2;
  const int lab = label[row];
  const float* wr = W + (size_t)lab * D;
  float d = v0 * wr[lane] + v1 * wr[lane + 64] + v2 * wr[lane + 128];
#pragma unroll
  for (int off = 32; off > 0; off >>= 1) {
    ss += __shfl_xor(ss, off, 64);
    d  += __shfl_xor(d,  off, 64);
  }
  if (lane == 0) {
    const float tgt   = d * rsqrtf(ss);
    const float numer = S_SCALE * (tgt - MARGIN);
    // swap label column: remove its plain-logit exp, add margin-adjusted exp
    const float se = sumexp[row] - __expf(S_SCALE * tgt) + __expf(numer);
    Lrow[row] = numer - logf(se);
  }
}

__global__ __launch_bounds__(256) void reduce_loss(const float* __restrict__ Lrow,
                                                   float* __restrict__ out) {
  const int tid = threadIdx.x;
  float s = 0.0f;
  for (int i = tid; i < N; i += 256) s += Lrow[i];
#pragma unroll
  for (int off = 32; off > 0; off >>= 1) s += __shfl_xor(s, off, 64);
  __shared__ float part[4];
  if ((tid & 63) == 0) part[tid >> 6] = s;
  __syncthreads();
  if (tid == 0) out[0] = -(part[0] + part[1] + part[2] + part[3]) / (float)N;
}

// ---------------- host ----------------------------------------------------
extern "C" void kernel_launch(void* const* d_in, const int* in_sizes, int n_in,
                              void* d_out, int out_size, void* d_ws, size_t ws_size,
                              hipStream_t stream) {
  const float* x     = (const float*)d_in[0];
  const float* W     = (const float*)d_in[1];
  const int*   label = (const int*)d_in[2];
  float*       out   = (float*)d_out;

  char* ws = (char*)d_ws;
  size_t off = 0;
  unsigned short* xnb = (unsigned short*)(ws + off); off += (size_t)N * D * 2;        // 768 KB
  unsigned short* Wb  = (unsigned short*)(ws + off); off += (size_t)NT16 * KT * TILE * 2; // 38.5 MB
  float* partial = (float*)(ws + off); off += (size_t)CX * N * 4;                      // 1.6 MB
  float* sumexp  = (float*)(ws + off); off += (size_t)N * 4;
  float* Lrow    = (float*)(ws + off);

  prep_x<<<N / 4, 256, 0, stream>>>(x, xnb);
  prep_w<<<NT16 / 4, 256, 0, stream>>>(W, Wb);

  dim3 grid(CX, RY);
  gemm_lse<<<grid, 512, 0, stream>>>(xnb, Wb, partial);

  reduce_partial<<<N / 256, 256, 0, stream>>>(partial, sumexp);
  finalize_rows<<<N / 4, 256, 0, stream>>>(x, W, label, sumexp, Lrow);
  reduce_loss<<<1, 256, 0, stream>>>(Lrow, out);
}

// Round 7
// 214.474 us; speedup vs baseline: 2.8215x; 1.1854x over previous
//
#include <hip/hip_runtime.h>
#include <stdint.h>

// AM-softmax loss, fused on MI355X (gfx950) — round 7.
//
// vs round 6 (131 us gemm; pipe work per block ran SERIALLY: 1 block/CU,
// 2 lockstep waves/SIMD -> MFMA idle during epilogue and vice versa):
//  * block = 4 waves (256 thr), wave tile 64 rows x 48 cols (tc=3):
//    ~160 VGPRs -> 3 waves/SIMD; A slab 128 rows (48 KB) + 2 KB rowsum ->
//    3 blocks/CU co-resident at staggered phases. Cross-block pipe overlap
//    (MFMA / VALU+exp / LDS) replaces intra-block lockstep.
//  * grid linearized cx = bid>>4: 16 consecutive blocks share one 72 KB Wb
//    chunk (~2 blocks/XCD) -> per-XCD L2 reuse of B.
//  * phantom cols exactly zero in Wb -> exp2(0)=1; epilogue mask deleted,
//    constant 416 subtracted at finalize. reduce_partial fused into
//    finalize_rows (one fewer launch, no memset).

constexpr int N  = 2048;
constexpr int D  = 192;               // K
constexpr int C  = 100000;
constexpr int KT = D / 32;            // 6 k-tiles of 32
constexpr int TILE = 512;             // elems per 16x32 fragment tile
constexpr int RT16 = C / 16;          // 6250 real 16-col tiles
constexpr int TPG = 12;               // 16-col tiles per block (4 waves x 3)
constexpr int CX = 523;               // col groups: 523*12 = 6276 tiles
constexpr int RY = 16;                // 128-row bands
constexpr int NT16 = CX * TPG;        // 6276 tiles = 100416 cols
constexpr float PHANTOM = (float)(NT16 * 16 - C);   // 416 exact ones

#define S_SCALE 30.0f
#define MARGIN  0.2f
#define S_LOG2E 43.2808512266689f     // 30 * log2(e)

using short8 = __attribute__((ext_vector_type(8))) short;   // 8 bf16 (4 VGPRs)
using f32x4  = __attribute__((ext_vector_type(4))) float;   // MFMA C/D

typedef __attribute__((address_space(1))) const void GV;
typedef __attribute__((address_space(3))) void LV;

__device__ inline unsigned short f2bf(float f) {  // fp32 -> bf16 RNE
  unsigned int u = __float_as_uint(f);
  u += 0x7fffu + ((u >> 16) & 1u);
  return (unsigned short)(u >> 16);
}

// packed fragment index (ushort units) for element (row r, k):
// tile (r>>4, k>>5), lane = (r&15) + ((k>>3)&3)*16, elem k&7.
__device__ inline int pack_idx(int r, int k) {
  return ((r >> 4) * KT + (k >> 5)) * TILE + (((k >> 3) & 3) * 16 + (r & 15)) * 8 + (k & 7);
}

// Sum across each 16-lane DPP row; result valid in all 16 lanes.
__device__ inline float row_sum16(float v) {
  int x;
  x = __float_as_int(v);
  v += __int_as_float(__builtin_amdgcn_update_dpp(0, x, 0x128, 0xF, 0xF, true)); // row_ror:8
  x = __float_as_int(v);
  v += __int_as_float(__builtin_amdgcn_update_dpp(0, x, 0x124, 0xF, 0xF, true)); // row_ror:4
  x = __float_as_int(v);
  v += __int_as_float(__builtin_amdgcn_update_dpp(0, x, 0x04E, 0xF, 0xF, true)); // quad_perm xor2
  x = __float_as_int(v);
  v += __int_as_float(__builtin_amdgcn_update_dpp(0, x, 0x0B1, 0xF, 0xF, true)); // quad_perm xor1
  return v;
}

// ---------------- prep: normalize x rows -> packed bf16 * S*log2e ---------
__global__ __launch_bounds__(256) void prep_x(const float* __restrict__ x,
                                              unsigned short* __restrict__ xnb) {
  const int row  = blockIdx.x * 4 + (threadIdx.x >> 6);
  const int lane = threadIdx.x & 63;
  const float* xr = x + (size_t)row * D;
  float v0 = xr[lane], v1 = xr[lane + 64], v2 = xr[lane + 128];
  float ss = v0 * v0 + v1 * v1 + v2 * v2;
#pragma unroll
  for (int off = 32; off > 0; off >>= 1) ss += __shfl_xor(ss, off, 64);
  const float inv = rsqrtf(ss) * S_LOG2E;   // fold exp scale into A
  xnb[pack_idx(row, lane)]       = f2bf(v0 * inv);
  xnb[pack_idx(row, lane + 64)]  = f2bf(v1 * inv);
  xnb[pack_idx(row, lane + 128)] = f2bf(v2 * inv);
}

// ---------------- prep: W fp32 -> fragment-packed bf16 Wb -----------------
// One wave per 16-col tile. Tiles >= RT16 are exactly zero (phantom classes:
// exp2(0)=1, corrected by the PHANTOM constant at finalize).
__global__ __launch_bounds__(256) void prep_w(const float* __restrict__ W,
                                              unsigned short* __restrict__ Wb) {
  const int t16  = blockIdx.x * 4 + (threadIdx.x >> 6);
  const int lane = threadIdx.x & 63;
  const int m = lane & 15, q = lane >> 4;
  unsigned short* dst = Wb + (size_t)t16 * KT * TILE + lane * 8;
  if (t16 < RT16) {
    const float* src = W + (size_t)(t16 * 16 + m) * D + q * 8;
#pragma unroll
    for (int ks = 0; ks < KT; ++ks) {
      const float4* s4 = (const float4*)(src + ks * 32);
      float4 f0 = s4[0], f1 = s4[1];
      short8 hv;
      hv[0] = (short)f2bf(f0.x); hv[1] = (short)f2bf(f0.y);
      hv[2] = (short)f2bf(f0.z); hv[3] = (short)f2bf(f0.w);
      hv[4] = (short)f2bf(f1.x); hv[5] = (short)f2bf(f1.y);
      hv[6] = (short)f2bf(f1.z); hv[7] = (short)f2bf(f1.w);
      *(short8*)(dst + (size_t)ks * TILE) = hv;
    }
  } else {
    const short8 z = {0, 0, 0, 0, 0, 0, 0, 0};
#pragma unroll
    for (int ks = 0; ks < KT; ++ks) *(short8*)(dst + (size_t)ks * TILE) = z;
  }
}

// ---------------- main fused GEMM + exp-rowsum ----------------------------
// 1-D grid of CX*RY blocks; cx = bid>>4, ry = bid&15 (16 consecutive blocks
// share one Wb chunk -> XCD L2 reuse). Block = 4 waves; wave w owns 48 cols
// (3 tiles, B in ~72 VGPRs); shared 128-row A slab in LDS; 2 rowsteps.
__global__ __launch_bounds__(256, 3) void gemm_lse(
    const unsigned short* __restrict__ xnb,  // packed [128 row-tiles][KT][512]
    const unsigned short* __restrict__ Wb,   // packed [NT16][KT][512]
    float* __restrict__ partial) {           // [CX][N]
  __shared__ alignas(16) unsigned short As[8 * KT * TILE];   // 48 KB
  __shared__ alignas(16) float rs_lds[4][128];               // 2 KB

  const int tid = threadIdx.x;
  const int bid = blockIdx.x;
  const int cx = bid >> 4, ry = bid & 15;

  // ---- DMA the 128-row A slab (48 KB contiguous, fragment-packed) ----
  const unsigned short* slab = xnb + (size_t)(ry * 8) * KT * TILE;
#pragma unroll
  for (int i = 0; i < 12; ++i) {             // 3072 x 16 B
    const int chunk = tid + i * 256;
    __builtin_amdgcn_global_load_lds(
        (GV*)((const char*)slab + (size_t)chunk * 16),
        (LV*)((char*)As + (size_t)chunk * 16), 16, 0, 0);
  }

  const int lane = tid & 63, wave = tid >> 6;
  const int m = lane & 15, quad = lane >> 4;

  // ---- B fragments -> registers (18 coalesced 1 KB wave-loads) ----
  short8 breg[3][KT];
#pragma unroll
  for (int tc = 0; tc < 3; ++tc)
#pragma unroll
    for (int ks = 0; ks < KT; ++ks)
      breg[tc][ks] = *(const short8*)(
          Wb + (size_t)((cx * TPG + wave * 3 + tc) * KT + ks) * TILE + lane * 8);

  __syncthreads();  // A slab ready (drains DMA); the ONLY pre-loop barrier

  const f32x4 zero4 = {0.0f, 0.0f, 0.0f, 0.0f};

  for (int rs = 0; rs < 2; ++rs) {           // 2 independent 64-row steps
    f32x4 acc[4][3];
#pragma unroll
    for (int a = 0; a < 4; ++a)
#pragma unroll
      for (int b = 0; b < 3; ++b) acc[a][b] = zero4;

#pragma unroll
    for (int ks = 0; ks < KT; ++ks) {
      short8 af[4];
#pragma unroll
      for (int tr = 0; tr < 4; ++tr)
        af[tr] = *(const short8*)(
            &As[((rs * 4 + tr) * KT + ks) * TILE + lane * 8]);
#pragma unroll
      for (int tr = 0; tr < 4; ++tr)
#pragma unroll
        for (int tc = 0; tc < 3; ++tc)
          acc[tr][tc] = __builtin_amdgcn_mfma_f32_16x16x32_bf16(
              af[tr], breg[tc][ks], acc[tr][tc], 0, 0, 0);
    }

    // ---- epilogue: exp2 (arg pre-scaled; phantom cols give exactly 1) ----
#pragma unroll
    for (int tr = 0; tr < 4; ++tr) {
      float rv0 = 0.f, rv1 = 0.f, rv2 = 0.f, rv3 = 0.f;
#pragma unroll
      for (int tc = 0; tc < 3; ++tc) {
        rv0 += __builtin_amdgcn_exp2f(acc[tr][tc][0]);
        rv1 += __builtin_amdgcn_exp2f(acc[tr][tc][1]);
        rv2 += __builtin_amdgcn_exp2f(acc[tr][tc][2]);
        rv3 += __builtin_amdgcn_exp2f(acc[tr][tc][3]);
      }
      rv0 = row_sum16(rv0);
      rv1 = row_sum16(rv1);
      rv2 = row_sum16(rv2);
      rv3 = row_sum16(rv3);
      if (m == 0) {
        float4 v = make_float4(rv0, rv1, rv2, rv3);
        *(float4*)(&rs_lds[wave][rs * 64 + tr * 16 + quad * 4]) = v;
      }
    }
  }

  __syncthreads();  // all waves' rowsums in LDS
  if (tid < 128) {
    const float s = rs_lds[0][tid] + rs_lds[1][tid] + rs_lds[2][tid] + rs_lds[3][tid];
    partial[(size_t)cx * N + ry * 128 + tid] = s;   // coalesced, exclusive
  }
}

// ---------------- per-row finalize (fused partial reduce) -----------------
// One wave per row: lanes gather this row's 523 partials AND recompute the
// fp32 target logit; single shuffle reduction covers both.
__global__ __launch_bounds__(256) void finalize_rows(
    const float* __restrict__ x, const float* __restrict__ W,
    const int* __restrict__ label, const float* __restrict__ partial,
    float* __restrict__ Lrow) {
  const int row  = blockIdx.x * 4 + (threadIdx.x >> 6);
  const int lane = threadIdx.x & 63;
  const float* xr = x + (size_t)row * D;
  float v0 = xr[lane], v1 = xr[lane + 64], v2 = xr[lane + 128];
  float ss = v0 * v0 + v1 * v1 + v2 * v2;
  const int lab = label[row];
  const float* wr = W + (size_t)lab * D;
  float d = v0 * wr[lane] + v1 * wr[lane + 64] + v2 * wr[lane + 128];
  float p = 0.0f;
  for (int s = lane; s < CX; s += 64) p += partial[(size_t)s * N + row];
#pragma unroll
  for (int off = 32; off > 0; off >>= 1) {
    ss += __shfl_xor(ss, off, 64);
    d  += __shfl_xor(d,  off, 64);
    p  += __shfl_xor(p,  off, 64);
  }
  if (lane == 0) {
    const float tgt   = d * rsqrtf(ss);
    const float numer = S_SCALE * (tgt - MARGIN);
    // remove phantom-ones, swap label column's exp for margin-adjusted exp
    const float se = p - PHANTOM - __expf(S_SCALE * tgt) + __expf(numer);
    Lrow[row] = numer - logf(se);
  }
}

__global__ __launch_bounds__(256) void reduce_loss(const float* __restrict__ Lrow,
                                                   float* __restrict__ out) {
  const int tid = threadIdx.x;
  float s = 0.0f;
  for (int i = tid; i < N; i += 256) s += Lrow[i];
#pragma unroll
  for (int off = 32; off > 0; off >>= 1) s += __shfl_xor(s, off, 64);
  __shared__ float part[4];
  if ((tid & 63) == 0) part[tid >> 6] = s;
  __syncthreads();
  if (tid == 0) out[0] = -(part[0] + part[1] + part[2] + part[3]) / (float)N;
}

// ---------------- host ----------------------------------------------------
extern "C" void kernel_launch(void* const* d_in, const int* in_sizes, int n_in,
                              void* d_out, int out_size, void* d_ws, size_t ws_size,
                              hipStream_t stream) {
  const float* x     = (const float*)d_in[0];
  const float* W     = (const float*)d_in[1];
  const int*   label = (const int*)d_in[2];
  float*       out   = (float*)d_out;

  char* ws = (char*)d_ws;
  size_t off = 0;
  unsigned short* xnb = (unsigned short*)(ws + off); off += (size_t)N * D * 2;            // 768 KB
  unsigned short* Wb  = (unsigned short*)(ws + off); off += (size_t)NT16 * KT * TILE * 2; // 38.6 MB
  float* partial = (float*)(ws + off); off += (size_t)CX * N * 4;                          // 4.3 MB
  float* Lrow    = (float*)(ws + off);

  prep_x<<<N / 4, 256, 0, stream>>>(x, xnb);
  prep_w<<<NT16 / 4, 256, 0, stream>>>(W, Wb);

  gemm_lse<<<CX * RY, 256, 0, stream>>>(xnb, Wb, partial);

  finalize_rows<<<N / 4, 256, 0, stream>>>(x, W, label, partial, Lrow);
  reduce_loss<<<1, 256, 0, stream>>>(Lrow, out);
}

// Round 8
// 211.987 us; speedup vs baseline: 2.8546x; 1.0117x over previous
//
#include <hip/hip_runtime.h>
#include <stdint.h>

// AM-softmax loss, fused on MI355X (gfx950) — round 8.
//
// vs round 7 (gemm 88 us; total 214 us with ~126 us in 5 small-kernel
// launches at ~25 us dispatch overhead each):
//  * 5 launches -> 3: prep_x + prep_w fused (block-id branch; also zeroes
//    out[0]); reduce_loss folded into finalize via one fp32 atomicAdd per
//    block (512 atomics total, out[0] pre-zeroed by prep).
//  * gemm: 4 bands of 64 rows per block, A double-buffered 2x24 KB (52 KB
//    LDS -> still 3 blocks/CU). DMA for band b+1 issued BEFORE compute of
//    band b, so the per-band barrier's vmcnt drain hits a completed DMA
//    (true prefetch; round 5's version barriered immediately after issue).
//    breg loads amortized over 256 rows; 4184 blocks -> startup 16x/CU.

constexpr int N  = 2048;
constexpr int D  = 192;               // K
constexpr int C  = 100000;
constexpr int KT = D / 32;            // 6 k-tiles of 32
constexpr int TILE = 512;             // elems per 16x32 fragment tile
constexpr int RT16 = C / 16;          // 6250 real 16-col tiles
constexpr int TPG = 12;               // 16-col tiles per block (4 waves x 3)
constexpr int CX = 523;               // col groups: 523*12 = 6276 tiles
constexpr int NT16 = CX * TPG;        // 6276 tiles = 100416 cols
constexpr float PHANTOM = (float)(NT16 * 16 - C);   // 416 exact ones
constexpr int BANDS = 4;              // 64-row bands per block
constexpr int RYB = N / (64 * BANDS); // 8 row groups
constexpr int BUF = 4 * KT * TILE;    // 12288 ushort = 24 KB per band buffer
constexpr int NXB = N / 4;            // 512 prep_x blocks

#define S_SCALE 30.0f
#define MARGIN  0.2f
#define S_LOG2E 43.2808512266689f     // 30 * log2(e)

using short8 = __attribute__((ext_vector_type(8))) short;   // 8 bf16 (4 VGPRs)
using f32x4  = __attribute__((ext_vector_type(4))) float;   // MFMA C/D

typedef __attribute__((address_space(1))) const void GV;
typedef __attribute__((address_space(3))) void LV;

__device__ inline unsigned short f2bf(float f) {  // fp32 -> bf16 RNE
  unsigned int u = __float_as_uint(f);
  u += 0x7fffu + ((u >> 16) & 1u);
  return (unsigned short)(u >> 16);
}

// packed fragment index (ushort units) for element (row r, k):
// tile (r>>4, k>>5), lane = (r&15) + ((k>>3)&3)*16, elem k&7.
__device__ inline int pack_idx(int r, int k) {
  return ((r >> 4) * KT + (k >> 5)) * TILE + (((k >> 3) & 3) * 16 + (r & 15)) * 8 + (k & 7);
}

// Sum across each 16-lane DPP row; result valid in all 16 lanes.
__device__ inline float row_sum16(float v) {
  int x;
  x = __float_as_int(v);
  v += __int_as_float(__builtin_amdgcn_update_dpp(0, x, 0x128, 0xF, 0xF, true)); // row_ror:8
  x = __float_as_int(v);
  v += __int_as_float(__builtin_amdgcn_update_dpp(0, x, 0x124, 0xF, 0xF, true)); // row_ror:4
  x = __float_as_int(v);
  v += __int_as_float(__builtin_amdgcn_update_dpp(0, x, 0x04E, 0xF, 0xF, true)); // quad_perm xor2
  x = __float_as_int(v);
  v += __int_as_float(__builtin_amdgcn_update_dpp(0, x, 0x0B1, 0xF, 0xF, true)); // quad_perm xor1
  return v;
}

// ---------------- fused prep: x-normalize + W pack (+ zero out[0]) --------
__global__ __launch_bounds__(256) void prep_all(
    const float* __restrict__ x, const float* __restrict__ W,
    unsigned short* __restrict__ xnb, unsigned short* __restrict__ Wb,
    float* __restrict__ out) {
  const int bid  = blockIdx.x;
  const int lane = threadIdx.x & 63;
  if (bid == 0 && threadIdx.x == 0) out[0] = 0.0f;   // for finalize atomics

  if (bid < NXB) {
    // ---- prep_x: normalize row, scale by S*log2e, pack fragments ----
    const int row = bid * 4 + (threadIdx.x >> 6);
    const float* xr = x + (size_t)row * D;
    float v0 = xr[lane], v1 = xr[lane + 64], v2 = xr[lane + 128];
    float ss = v0 * v0 + v1 * v1 + v2 * v2;
#pragma unroll
    for (int off = 32; off > 0; off >>= 1) ss += __shfl_xor(ss, off, 64);
    const float inv = rsqrtf(ss) * S_LOG2E;
    xnb[pack_idx(row, lane)]       = f2bf(v0 * inv);
    xnb[pack_idx(row, lane + 64)]  = f2bf(v1 * inv);
    xnb[pack_idx(row, lane + 128)] = f2bf(v2 * inv);
  } else {
    // ---- prep_w: one wave per 16-col tile; tiles >= RT16 exactly zero ----
    const int t16 = (bid - NXB) * 4 + (threadIdx.x >> 6);
    const int m = lane & 15, q = lane >> 4;
    unsigned short* dst = Wb + (size_t)t16 * KT * TILE + lane * 8;
    if (t16 < RT16) {
      const float* src = W + (size_t)(t16 * 16 + m) * D + q * 8;
#pragma unroll
      for (int ks = 0; ks < KT; ++ks) {
        const float4* s4 = (const float4*)(src + ks * 32);
        float4 f0 = s4[0], f1 = s4[1];
        short8 hv;
        hv[0] = (short)f2bf(f0.x); hv[1] = (short)f2bf(f0.y);
        hv[2] = (short)f2bf(f0.z); hv[3] = (short)f2bf(f0.w);
        hv[4] = (short)f2bf(f1.x); hv[5] = (short)f2bf(f1.y);
        hv[6] = (short)f2bf(f1.z); hv[7] = (short)f2bf(f1.w);
        *(short8*)(dst + (size_t)ks * TILE) = hv;
      }
    } else {
      const short8 z = {0, 0, 0, 0, 0, 0, 0, 0};
#pragma unroll
      for (int ks = 0; ks < KT; ++ks) *(short8*)(dst + (size_t)ks * TILE) = z;
    }
  }
}

// ---------------- main fused GEMM + exp-rowsum ----------------------------
// 1-D grid CX*RYB; cx = bid>>3, ry = bid&7 (8 consecutive blocks share one
// Wb chunk -> L2 reuse). Block = 4 waves; wave owns 48 cols (B in regs).
// 4 bands of 64 rows, A double-buffered (24 KB each), prefetch ahead.
__global__ __launch_bounds__(256, 3) void gemm_lse(
    const unsigned short* __restrict__ xnb,  // packed [128 row-tiles][KT][512]
    const unsigned short* __restrict__ Wb,   // packed [NT16][KT][512]
    float* __restrict__ partial) {           // [CX][N]
  __shared__ alignas(16) unsigned short As[2 * BUF];   // 48 KB (double buffer)
  __shared__ alignas(16) float rs_lds[4][256];         // 4 KB

  const int tid = threadIdx.x;
  const int bid = blockIdx.x;
  const int cx = bid >> 3, ry = bid & 7;

  // ---- issue DMA for band 0 into buf 0 (24 KB, contiguous packed) ----
  {
    const unsigned short* slab = xnb + (size_t)(ry * BANDS) * BUF;
#pragma unroll
    for (int i = 0; i < 6; ++i) {            // 1536 x 16 B
      const int chunk = tid + i * 256;
      __builtin_amdgcn_global_load_lds(
          (GV*)((const char*)slab + (size_t)chunk * 16),
          (LV*)((char*)As + (size_t)chunk * 16), 16, 0, 0);
    }
  }

  const int lane = tid & 63, wave = tid >> 6;
  const int m = lane & 15, quad = lane >> 4;

  // ---- B fragments -> registers (18 coalesced 1 KB wave-loads) ----
  short8 breg[3][KT];
#pragma unroll
  for (int tc = 0; tc < 3; ++tc)
#pragma unroll
    for (int ks = 0; ks < KT; ++ks)
      breg[tc][ks] = *(const short8*)(
          Wb + (size_t)((cx * TPG + wave * 3 + tc) * KT + ks) * TILE + lane * 8);

  const f32x4 zero4 = {0.0f, 0.0f, 0.0f, 0.0f};

  for (int b = 0; b < BANDS; ++b) {
    __syncthreads();   // drains vmcnt: band b's DMA (issued a full band ago)

    // prefetch band b+1 into the other buffer BEFORE compute of band b
    if (b + 1 < BANDS) {
      const unsigned short* slab = xnb + (size_t)(ry * BANDS + b + 1) * BUF;
      char* dst = (char*)&As[((b + 1) & 1) * BUF];
#pragma unroll
      for (int i = 0; i < 6; ++i) {
        const int chunk = tid + i * 256;
        __builtin_amdgcn_global_load_lds(
            (GV*)((const char*)slab + (size_t)chunk * 16),
            (LV*)(dst + (size_t)chunk * 16), 16, 0, 0);
      }
    }

    const unsigned short* Ab = &As[(b & 1) * BUF];

    f32x4 acc[4][3];
#pragma unroll
    for (int a = 0; a < 4; ++a)
#pragma unroll
      for (int c = 0; c < 3; ++c) acc[a][c] = zero4;

#pragma unroll
    for (int ks = 0; ks < KT; ++ks) {
      short8 af[4];
#pragma unroll
      for (int tr = 0; tr < 4; ++tr)
        af[tr] = *(const short8*)(&Ab[(tr * KT + ks) * TILE + lane * 8]);
#pragma unroll
      for (int tr = 0; tr < 4; ++tr)
#pragma unroll
        for (int tc = 0; tc < 3; ++tc)
          acc[tr][tc] = __builtin_amdgcn_mfma_f32_16x16x32_bf16(
              af[tr], breg[tc][ks], acc[tr][tc], 0, 0, 0);
    }

    // ---- epilogue: exp2 (arg pre-scaled; phantom cols give exactly 1) ----
#pragma unroll
    for (int tr = 0; tr < 4; ++tr) {
      float rv0 = 0.f, rv1 = 0.f, rv2 = 0.f, rv3 = 0.f;
#pragma unroll
      for (int tc = 0; tc < 3; ++tc) {
        rv0 += __builtin_amdgcn_exp2f(acc[tr][tc][0]);
        rv1 += __builtin_amdgcn_exp2f(acc[tr][tc][1]);
        rv2 += __builtin_amdgcn_exp2f(acc[tr][tc][2]);
        rv3 += __builtin_amdgcn_exp2f(acc[tr][tc][3]);
      }
      rv0 = row_sum16(rv0);
      rv1 = row_sum16(rv1);
      rv2 = row_sum16(rv2);
      rv3 = row_sum16(rv3);
      if (m == 0) {
        float4 v = make_float4(rv0, rv1, rv2, rv3);
        *(float4*)(&rs_lds[wave][b * 64 + tr * 16 + quad * 4]) = v;
      }
    }
  }

  __syncthreads();  // all waves' rowsums in LDS (also drains nothing extra)
  if (tid < 256) {
    const float s = rs_lds[0][tid] + rs_lds[1][tid] + rs_lds[2][tid] + rs_lds[3][tid];
    partial[(size_t)cx * N + ry * 256 + tid] = s;   // coalesced, exclusive
  }
}

// ---------------- finalize: per-row loss + in-kernel mean reduce ----------
// One wave per row (4 rows/block): gather 523 partials + fp32 target logit in
// one shuffle reduction; block-sum -> one atomicAdd into out[0] (pre-zeroed).
__global__ __launch_bounds__(256) void finalize_rows(
    const float* __restrict__ x, const float* __restrict__ W,
    const int* __restrict__ label, const float* __restrict__ partial,
    float* __restrict__ out) {
  const int row  = blockIdx.x * 4 + (threadIdx.x >> 6);
  const int lane = threadIdx.x & 63;
  const float* xr = x + (size_t)row * D;
  float v0 = xr[lane], v1 = xr[lane + 64], v2 = xr[lane + 128];
  float ss = v0 * v0 + v1 * v1 + v2 * v2;
  const int lab = label[row];
  const float* wr = W + (size_t)lab * D;
  float d = v0 * wr[lane] + v1 * wr[lane + 64] + v2 * wr[lane + 128];
  float p = 0.0f;
  for (int s = lane; s < CX; s += 64) p += partial[(size_t)s * N + row];
#pragma unroll
  for (int off = 32; off > 0; off >>= 1) {
    ss += __shfl_xor(ss, off, 64);
    d  += __shfl_xor(d,  off, 64);
    p  += __shfl_xor(p,  off, 64);
  }
  __shared__ float part[4];
  if (lane == 0) {
    const float tgt   = d * rsqrtf(ss);
    const float numer = S_SCALE * (tgt - MARGIN);
    // remove phantom-ones, swap label column's exp for margin-adjusted exp
    const float se = p - PHANTOM - __expf(S_SCALE * tgt) + __expf(numer);
    part[threadIdx.x >> 6] = numer - logf(se);
  }
  __syncthreads();
  if (threadIdx.x == 0) {
    const float blocksum = part[0] + part[1] + part[2] + part[3];
    atomicAdd(out, -blocksum * (1.0f / (float)N));
  }
}

// ---------------- host ----------------------------------------------------
extern "C" void kernel_launch(void* const* d_in, const int* in_sizes, int n_in,
                              void* d_out, int out_size, void* d_ws, size_t ws_size,
                              hipStream_t stream) {
  const float* x     = (const float*)d_in[0];
  const float* W     = (const float*)d_in[1];
  const int*   label = (const int*)d_in[2];
  float*       out   = (float*)d_out;

  char* ws = (char*)d_ws;
  size_t off = 0;
  unsigned short* xnb = (unsigned short*)(ws + off); off += (size_t)N * D * 2;            // 768 KB
  unsigned short* Wb  = (unsigned short*)(ws + off); off += (size_t)NT16 * KT * TILE * 2; // 38.6 MB
  float* partial = (float*)(ws + off); off += (size_t)CX * N * 4;                          // 4.3 MB

  prep_all<<<NXB + NT16 / 4, 256, 0, stream>>>(x, W, xnb, Wb, out);

  gemm_lse<<<CX * RYB, 256, 0, stream>>>(xnb, Wb, partial);

  finalize_rows<<<N / 4, 256, 0, stream>>>(x, W, label, partial, out);
}